// Round 2
// baseline (274807.764 us; speedup 1.0000x reference)
//
#include <hip/hip_runtime.h>
#include <hip/hip_bf16.h>

// Problem constants (from setup_inputs)
#define BB 8
#define SS 2048
#define DD 1024
#define VV 32000
#define DC 512
#define MM (BB * SS)          // 16384 rows
#define NTOT 3072             // 3 x 1024 output columns

// ---------------------------------------------------------------------------
// init: zero the barrier counters (ws is poisoned 0xAA before every call)
// ---------------------------------------------------------------------------
__global__ void init_kernel(unsigned* ctrs) {
  ctrs[threadIdx.x] = 0u;
}

// ---------------------------------------------------------------------------
// GEMM: XP[m][bs][j] = gather(emb)[bs] @ W_m[0:D] + b_m      (fp32)
// A is gathered on the fly: A[bs][k] = (k<512? emb_r : emb_i)[ids[bs]][k%512]
// 128x128 tile, BK=16, 256 threads, 8x8 acc/thread.
// ---------------------------------------------------------------------------
#define GM_BM 128
#define GM_BN 128
#define GM_BK 16

__launch_bounds__(256)
__global__ void gemm_xproj(const int* __restrict__ ids,
                           const float* __restrict__ emb_r,
                           const float* __restrict__ emb_i,
                           const float* __restrict__ Wr,
                           const float* __restrict__ Wu,
                           const float* __restrict__ Wc,
                           const float* __restrict__ br,
                           const float* __restrict__ bu,
                           const float* __restrict__ bc,
                           float* __restrict__ XP) {
  __shared__ float A_lds[GM_BK][GM_BM + 4];
  __shared__ float B_lds[GM_BK][GM_BN + 4];
  __shared__ int ids_lds[GM_BM];

  const int NT = NTOT / GM_BN;   // 24
  int wg = blockIdx.x;
  int nt = wg % NT, mt = wg / NT;
  int n0 = nt * GM_BN;
  int midx = n0 / DD;            // which matrix (0=r,1=u,2=c)
  int nj0 = n0 % DD;
  const float* W    = (midx == 0) ? Wr : ((midx == 1) ? Wu : Wc);
  const float* bias = (midx == 0) ? br : ((midx == 1) ? bu : bc);
  int m0 = mt * GM_BM;
  int tid = threadIdx.x;

  if (tid < GM_BM) ids_lds[tid] = ids[m0 + tid];
  __syncthreads();

  int tx = tid & 15, ty = tid >> 4;   // tx: col-oct 0..15, ty: row-oct 0..15
  float acc[8][8];
#pragma unroll
  for (int r = 0; r < 8; ++r)
#pragma unroll
    for (int c = 0; c < 8; ++c) acc[r][c] = 0.f;

  int lm = tid >> 1;            // A-load row 0..127
  int lk8 = (tid & 1) * 8;      // k offset 0 or 8
  int bkk = tid >> 4;           // B-load row 0..15
  int bn8 = (tid & 15) * 8;     // B-load col base

  for (int k0 = 0; k0 < DD; k0 += GM_BK) {
    int id = ids_lds[lm];
    const float* ebase = (k0 < DC) ? emb_r : emb_i;
    int col0 = k0 - ((k0 < DC) ? 0 : DC);
    float4 a0 = *(const float4*)&ebase[(size_t)id * DC + col0 + lk8];
    float4 a1 = *(const float4*)&ebase[(size_t)id * DC + col0 + lk8 + 4];
    float4 b0 = *(const float4*)&W[(size_t)(k0 + bkk) * DD + nj0 + bn8];
    float4 b1 = *(const float4*)&W[(size_t)(k0 + bkk) * DD + nj0 + bn8 + 4];
    __syncthreads();  // all reads of previous tile done
    A_lds[lk8 + 0][lm] = a0.x; A_lds[lk8 + 1][lm] = a0.y;
    A_lds[lk8 + 2][lm] = a0.z; A_lds[lk8 + 3][lm] = a0.w;
    A_lds[lk8 + 4][lm] = a1.x; A_lds[lk8 + 5][lm] = a1.y;
    A_lds[lk8 + 6][lm] = a1.z; A_lds[lk8 + 7][lm] = a1.w;
    *(float4*)&B_lds[bkk][bn8] = b0;
    *(float4*)&B_lds[bkk][bn8 + 4] = b1;
    __syncthreads();
#pragma unroll
    for (int kk = 0; kk < GM_BK; ++kk) {
      float4 av0 = *(float4*)&A_lds[kk][ty * 8];
      float4 av1 = *(float4*)&A_lds[kk][ty * 8 + 4];
      float4 bv0 = *(float4*)&B_lds[kk][tx * 8];
      float4 bv1 = *(float4*)&B_lds[kk][tx * 8 + 4];
      float a[8] = {av0.x, av0.y, av0.z, av0.w, av1.x, av1.y, av1.z, av1.w};
      float b[8] = {bv0.x, bv0.y, bv0.z, bv0.w, bv1.x, bv1.y, bv1.z, bv1.w};
#pragma unroll
      for (int r = 0; r < 8; ++r)
#pragma unroll
        for (int c = 0; c < 8; ++c) acc[r][c] += a[r] * b[c];
    }
  }

  float4 bv0 = *(const float4*)&bias[nj0 + tx * 8];
  float4 bv1 = *(const float4*)&bias[nj0 + tx * 8 + 4];
#pragma unroll
  for (int r = 0; r < 8; ++r) {
    float4 o0, o1;
    o0.x = acc[r][0] + bv0.x; o0.y = acc[r][1] + bv0.y;
    o0.z = acc[r][2] + bv0.z; o0.w = acc[r][3] + bv0.w;
    o1.x = acc[r][4] + bv1.x; o1.y = acc[r][5] + bv1.y;
    o1.z = acc[r][6] + bv1.z; o1.w = acc[r][7] + bv1.w;
    float* ob = &XP[((size_t)midx * MM + (m0 + ty * 8 + r)) * DD + nj0 + tx * 8];
    *(float4*)&ob[0] = o0;
    *(float4*)&ob[4] = o1;
  }
}

// ---------------------------------------------------------------------------
// Recurrent scan. 256 WGs x 512 threads. Group g = blockIdx%8 owns batch g
// (blockIdx%8 ~ XCD id if round-robin placement -> group-local L2 traffic).
// Each WG w=blockIdx/8 owns output columns [w*32, w*32+32).
// h-side weights held in registers: phase A (r,u) 128 VGPR, phase B (c) 64 VGPR.
// Two device-scope counter barriers per group per step. Spin loops carry a
// wall-clock bailout so a sync bug degrades to wrong-output, not a hang.
// ---------------------------------------------------------------------------
__device__ __forceinline__ float sigmoidf_(float x) {
  return 1.f / (1.f + __expf(-x));
}

__launch_bounds__(512)
__global__ void scan_kernel(const float* __restrict__ XP,
                            const float* __restrict__ Wr,
                            const float* __restrict__ Wu,
                            const float* __restrict__ Wc,
                            float* __restrict__ hs,
                            float* __restrict__ r_buf,
                            unsigned* __restrict__ ctrs) {
  __shared__ float h_lds[DD];
  __shared__ float g_lds[DD];
  __shared__ float u_stage[32];

  int wg = blockIdx.x;
  int b = wg & 7;
  int w = wg >> 3;            // 0..31
  int tid = threadIdx.x;
  int wv = tid >> 6;          // wave 0..7
  int l = tid & 63;           // lane

  // ---- phase A layout: 16 groups (8 r + 8 u) x 4 cols, 32 k-lanes each ----
  int ga = wv * 2 + (l >> 5); // 0..15
  int sA = l & 31;
  bool isR = (ga < 8);
  int gA = isR ? ga : (ga - 8);      // 0..7
  int jA = w * 32 + gA * 4;          // global col base (4 cols)
  const float* WA = isR ? Wr : Wu;

  float4 wAv[32];                    // weights: k = sA + 32*kk
#pragma unroll
  for (int kk = 0; kk < 32; ++kk)
    wAv[kk] = *(const float4*)&WA[(size_t)(DD + sA + 32 * kk) * DD + jA];

  // ---- phase B layout: wave wv owns 4 cols, full 64-lane K reduce ----
  int jB = w * 32 + wv * 4;
  float4 wBv[16];                    // weights: k = l + 64*i
#pragma unroll
  for (int i = 0; i < 16; ++i)
    wBv[i] = *(const float4*)&Wc[(size_t)(DD + l + 64 * i) * DD + jB];

  unsigned* ctrA = &ctrs[b * 32];
  unsigned* ctrB = &ctrs[512 + b * 32];

  const float* xpR = XP + ((size_t)0 * BB + b) * SS * DD;
  const float* xpU = XP + ((size_t)1 * BB + b) * SS * DD;
  const float* xpC = XP + ((size_t)2 * BB + b) * SS * DD;
  float* hsb = hs + (size_t)b * SS * DD;
  float* rb = r_buf + (size_t)b * DD;

  long long wc0 = wall_clock64();
  const long long BUDGET = 2000000000LL;  // hang bailout only (~20 s)

  for (int t = 0; t < SS; ++t) {
    // prefetch xp (independent of h — overlaps the spin)
    float4 xpA, xpC4;
    if (sA == 0) xpA = *(const float4*)&(isR ? xpR : xpU)[(size_t)t * DD + jA];
    if (l == 0) xpC4 = *(const float4*)&xpC[(size_t)t * DD + jB];

    // ---- wait for h_{t-1} (all 32 WGs of this group finished step t-1) ----
    if (t > 0) {
      if (tid == 0) {
        unsigned target = (unsigned)(32 * t);
        while (__hip_atomic_load(ctrB, __ATOMIC_ACQUIRE, __HIP_MEMORY_SCOPE_AGENT) < target) {
          if (wall_clock64() - wc0 > BUDGET) break;
          __builtin_amdgcn_s_sleep(2);
        }
      }
      __syncthreads();
      __threadfence();
    }

    // stage h into LDS (t=0: zeros)
    float4 hv4;
    if (tid < 256) {
      if (t == 0) { hv4.x = hv4.y = hv4.z = hv4.w = 0.f; }
      else hv4 = *(const float4*)&hsb[(size_t)(t - 1) * DD + tid * 4];
      *(float4*)&h_lds[tid * 4] = hv4;
    }
    __syncthreads();

    // ---- phase A: r,u = sigmoid(xp + h @ W_h) ----
    float a0 = 0.f, a1 = 0.f, a2 = 0.f, a3 = 0.f;
#pragma unroll
    for (int kk = 0; kk < 32; ++kk) {
      float hk = h_lds[sA + 32 * kk];
      float4 wv4 = wAv[kk];
      a0 += hk * wv4.x; a1 += hk * wv4.y; a2 += hk * wv4.z; a3 += hk * wv4.w;
    }
#pragma unroll
    for (int m = 16; m >= 1; m >>= 1) {
      a0 += __shfl_xor(a0, m); a1 += __shfl_xor(a1, m);
      a2 += __shfl_xor(a2, m); a3 += __shfl_xor(a3, m);
    }
    if (sA == 0) {
      float4 v;
      v.x = sigmoidf_(a0 + xpA.x); v.y = sigmoidf_(a1 + xpA.y);
      v.z = sigmoidf_(a2 + xpA.z); v.w = sigmoidf_(a3 + xpA.w);
      if (isR) *(float4*)&rb[jA] = v;
      else *(float4*)&u_stage[gA * 4] = v;
    }
    __threadfence();
    __syncthreads();
    if (tid == 0)
      __hip_atomic_fetch_add(ctrA, 1u, __ATOMIC_RELEASE, __HIP_MEMORY_SCOPE_AGENT);

    // ---- wait for full r ----
    if (tid == 0) {
      unsigned target = (unsigned)(32 * (t + 1));
      while (__hip_atomic_load(ctrA, __ATOMIC_ACQUIRE, __HIP_MEMORY_SCOPE_AGENT) < target) {
        if (wall_clock64() - wc0 > BUDGET) break;
        __builtin_amdgcn_s_sleep(2);
      }
    }
    __syncthreads();
    __threadfence();

    // stage g = r * h
    if (tid < 256) {
      float4 r4 = *(const float4*)&rb[tid * 4];
      float4 g4;
      g4.x = r4.x * hv4.x; g4.y = r4.y * hv4.y;
      g4.z = r4.z * hv4.z; g4.w = r4.w * hv4.w;
      *(float4*)&g_lds[tid * 4] = g4;
    }
    __syncthreads();

    // ---- phase B: c = tanh(xp + (r*h) @ Wc_h); h' = (1-u)h + u c ----
    float c0 = 0.f, c1 = 0.f, c2 = 0.f, c3 = 0.f;
#pragma unroll
    for (int i = 0; i < 16; ++i) {
      float gk = g_lds[l + 64 * i];
      float4 wv4 = wBv[i];
      c0 += gk * wv4.x; c1 += gk * wv4.y; c2 += gk * wv4.z; c3 += gk * wv4.w;
    }
#pragma unroll
    for (int m = 32; m >= 1; m >>= 1) {
      c0 += __shfl_xor(c0, m); c1 += __shfl_xor(c1, m);
      c2 += __shfl_xor(c2, m); c3 += __shfl_xor(c3, m);
    }
    if (l == 0) {
      float4 cc;
      cc.x = tanhf(c0 + xpC4.x); cc.y = tanhf(c1 + xpC4.y);
      cc.z = tanhf(c2 + xpC4.z); cc.w = tanhf(c3 + xpC4.w);
      float4 uu = *(float4*)&u_stage[wv * 4];
      float4 hh = *(float4*)&h_lds[jB];
      float4 hn;
      hn.x = (1.f - uu.x) * hh.x + uu.x * cc.x;
      hn.y = (1.f - uu.y) * hh.y + uu.y * cc.y;
      hn.z = (1.f - uu.z) * hh.z + uu.z * cc.z;
      hn.w = (1.f - uu.w) * hh.w + uu.w * cc.w;
      *(float4*)&hsb[(size_t)t * DD + jB] = hn;
    }
    __threadfence();
    __syncthreads();
    if (tid == 0)
      __hip_atomic_fetch_add(ctrB, 1u, __ATOMIC_RELEASE, __HIP_MEMORY_SCOPE_AGENT);
  }
}

// ---------------------------------------------------------------------------
// 6 LayerNorms over halves of hs. One wave per (b,s,half); 3 outputs each.
// ---------------------------------------------------------------------------
__launch_bounds__(256)
__global__ void ln_kernel(const float* __restrict__ hs,
                          const float* __restrict__ ln_scale,
                          const float* __restrict__ ln_bias,
                          float* __restrict__ out) {
  int wv = threadIdx.x >> 6, l = threadIdx.x & 63;
  int row = blockIdx.x * 4 + wv;   // 0..32767
  int half = row & 1;
  int bs = row >> 1;               // 0..16383

  const float* x = &hs[(size_t)bs * DD + half * DC];
  float4 v0 = *(const float4*)&x[l * 8];
  float4 v1 = *(const float4*)&x[l * 8 + 4];
  float sum = v0.x + v0.y + v0.z + v0.w + v1.x + v1.y + v1.z + v1.w;
  float sq = v0.x * v0.x + v0.y * v0.y + v0.z * v0.z + v0.w * v0.w +
             v1.x * v1.x + v1.y * v1.y + v1.z * v1.z + v1.w * v1.w;
#pragma unroll
  for (int m = 32; m >= 1; m >>= 1) {
    sum += __shfl_xor(sum, m);
    sq += __shfl_xor(sq, m);
  }
  float mu = sum * (1.f / 512.f);
  float var = sq * (1.f / 512.f) - mu * mu;
  float rs = rsqrtf(var + 1e-6f);

#pragma unroll
  for (int rep = 0; rep < 3; ++rep) {
    int i = half + rep * 2;
    float4 s0 = *(const float4*)&ln_scale[i * DC + l * 8];
    float4 s1 = *(const float4*)&ln_scale[i * DC + l * 8 + 4];
    float4 b0 = *(const float4*)&ln_bias[i * DC + l * 8];
    float4 b1 = *(const float4*)&ln_bias[i * DC + l * 8 + 4];
    float4 o0, o1;
    o0.x = (v0.x - mu) * rs * s0.x + b0.x;
    o0.y = (v0.y - mu) * rs * s0.y + b0.y;
    o0.z = (v0.z - mu) * rs * s0.z + b0.z;
    o0.w = (v0.w - mu) * rs * s0.w + b0.w;
    o1.x = (v1.x - mu) * rs * s1.x + b1.x;
    o1.y = (v1.y - mu) * rs * s1.y + b1.y;
    o1.z = (v1.z - mu) * rs * s1.z + b1.z;
    o1.w = (v1.w - mu) * rs * s1.w + b1.w;
    float* ob = &out[((size_t)i * MM + bs) * DC + l * 8];
    *(float4*)&ob[0] = o0;
    *(float4*)&ob[4] = o1;
  }
}

// ---------------------------------------------------------------------------
extern "C" void kernel_launch(void* const* d_in, const int* in_sizes, int n_in,
                              void* d_out, int out_size, void* d_ws, size_t ws_size,
                              hipStream_t stream) {
  const int* ids = (const int*)d_in[0];
  const float* emb_r = (const float*)d_in[1];
  const float* emb_i = (const float*)d_in[2];
  const float* Wr = (const float*)d_in[3];
  const float* br = (const float*)d_in[4];
  const float* Wu = (const float*)d_in[5];
  const float* bu = (const float*)d_in[6];
  const float* Wc = (const float*)d_in[7];
  const float* bc = (const float*)d_in[8];
  const float* ln_s = (const float*)d_in[9];
  const float* ln_b = (const float*)d_in[10];
  float* out = (float*)d_out;

  // ws layout (floats): XP[3][16384][1024] | hs[16384][1024] | r_buf[8][1024] | ctrs
  // total ~257 MB
  float* XP = (float*)d_ws;
  float* hs = XP + (size_t)3 * MM * DD;
  float* rb = hs + (size_t)MM * DD;
  unsigned* ctrs = (unsigned*)(rb + BB * DD);

  hipLaunchKernelGGL(init_kernel, dim3(1), dim3(1024), 0, stream, ctrs);
  hipLaunchKernelGGL(gemm_xproj, dim3((MM / GM_BM) * (NTOT / GM_BN)), dim3(256), 0, stream,
                     ids, emb_r, emb_i, Wr, Wu, Wc, br, bu, bc, XP);
  hipLaunchKernelGGL(scan_kernel, dim3(256), dim3(512), 0, stream,
                     XP, Wr, Wu, Wc, hs, rb, ctrs);
  hipLaunchKernelGGL(ln_kernel, dim3(32768 / 4), dim3(256), 0, stream,
                     hs, ln_s, ln_b, out);
}

// Round 3
// 32909.134 us; speedup vs baseline: 8.3505x; 8.3505x over previous
//
#include <hip/hip_runtime.h>
#include <hip/hip_bf16.h>

// Problem constants (from setup_inputs)
#define BB 8
#define SS 2048
#define DD 1024
#define VV 32000
#define DC 512
#define MM (BB * SS)          // 16384 rows
#define NTOT 3072             // 3 x 1024 output columns

// ---------------------------------------------------------------------------
// init: zero the barrier counters (ws is poisoned 0xAA before every call)
// ---------------------------------------------------------------------------
__global__ void init_kernel(unsigned* ctrs) {
  ctrs[threadIdx.x] = 0u;
}

// ---------------------------------------------------------------------------
// GEMM: XP[m][bs][j] = gather(emb)[bs] @ W_m[0:D] + b_m      (fp32)
// A is gathered on the fly: A[bs][k] = (k<512? emb_r : emb_i)[ids[bs]][k%512]
// 128x128 tile, BK=16, 256 threads, 8x8 acc/thread.  (unchanged this round)
// ---------------------------------------------------------------------------
#define GM_BM 128
#define GM_BN 128
#define GM_BK 16

__launch_bounds__(256)
__global__ void gemm_xproj(const int* __restrict__ ids,
                           const float* __restrict__ emb_r,
                           const float* __restrict__ emb_i,
                           const float* __restrict__ Wr,
                           const float* __restrict__ Wu,
                           const float* __restrict__ Wc,
                           const float* __restrict__ br,
                           const float* __restrict__ bu,
                           const float* __restrict__ bc,
                           float* __restrict__ XP) {
  __shared__ float A_lds[GM_BK][GM_BM + 4];
  __shared__ float B_lds[GM_BK][GM_BN + 4];
  __shared__ int ids_lds[GM_BM];

  const int NT = NTOT / GM_BN;   // 24
  int wg = blockIdx.x;
  int nt = wg % NT, mt = wg / NT;
  int n0 = nt * GM_BN;
  int midx = n0 / DD;            // which matrix (0=r,1=u,2=c)
  int nj0 = n0 % DD;
  const float* W    = (midx == 0) ? Wr : ((midx == 1) ? Wu : Wc);
  const float* bias = (midx == 0) ? br : ((midx == 1) ? bu : bc);
  int m0 = mt * GM_BM;
  int tid = threadIdx.x;

  if (tid < GM_BM) ids_lds[tid] = ids[m0 + tid];
  __syncthreads();

  int tx = tid & 15, ty = tid >> 4;
  float acc[8][8];
#pragma unroll
  for (int r = 0; r < 8; ++r)
#pragma unroll
    for (int c = 0; c < 8; ++c) acc[r][c] = 0.f;

  int lm = tid >> 1;            // A-load row 0..127
  int lk8 = (tid & 1) * 8;      // k offset 0 or 8
  int bkk = tid >> 4;           // B-load row 0..15
  int bn8 = (tid & 15) * 8;     // B-load col base

  for (int k0 = 0; k0 < DD; k0 += GM_BK) {
    int id = ids_lds[lm];
    const float* ebase = (k0 < DC) ? emb_r : emb_i;
    int col0 = k0 - ((k0 < DC) ? 0 : DC);
    float4 a0 = *(const float4*)&ebase[(size_t)id * DC + col0 + lk8];
    float4 a1 = *(const float4*)&ebase[(size_t)id * DC + col0 + lk8 + 4];
    float4 b0 = *(const float4*)&W[(size_t)(k0 + bkk) * DD + nj0 + bn8];
    float4 b1 = *(const float4*)&W[(size_t)(k0 + bkk) * DD + nj0 + bn8 + 4];
    __syncthreads();  // all reads of previous tile done
    A_lds[lk8 + 0][lm] = a0.x; A_lds[lk8 + 1][lm] = a0.y;
    A_lds[lk8 + 2][lm] = a0.z; A_lds[lk8 + 3][lm] = a0.w;
    A_lds[lk8 + 4][lm] = a1.x; A_lds[lk8 + 5][lm] = a1.y;
    A_lds[lk8 + 6][lm] = a1.z; A_lds[lk8 + 7][lm] = a1.w;
    *(float4*)&B_lds[bkk][bn8] = b0;
    *(float4*)&B_lds[bkk][bn8 + 4] = b1;
    __syncthreads();
#pragma unroll
    for (int kk = 0; kk < GM_BK; ++kk) {
      float4 av0 = *(float4*)&A_lds[kk][ty * 8];
      float4 av1 = *(float4*)&A_lds[kk][ty * 8 + 4];
      float4 bv0 = *(float4*)&B_lds[kk][tx * 8];
      float4 bv1 = *(float4*)&B_lds[kk][tx * 8 + 4];
      float a[8] = {av0.x, av0.y, av0.z, av0.w, av1.x, av1.y, av1.z, av1.w};
      float b[8] = {bv0.x, bv0.y, bv0.z, bv0.w, bv1.x, bv1.y, bv1.z, bv1.w};
#pragma unroll
      for (int r = 0; r < 8; ++r)
#pragma unroll
        for (int c = 0; c < 8; ++c) acc[r][c] += a[r] * b[c];
    }
  }

  float4 bv0 = *(const float4*)&bias[nj0 + tx * 8];
  float4 bv1 = *(const float4*)&bias[nj0 + tx * 8 + 4];
#pragma unroll
  for (int r = 0; r < 8; ++r) {
    float4 o0, o1;
    o0.x = acc[r][0] + bv0.x; o0.y = acc[r][1] + bv0.y;
    o0.z = acc[r][2] + bv0.z; o0.w = acc[r][3] + bv0.w;
    o1.x = acc[r][4] + bv1.x; o1.y = acc[r][5] + bv1.y;
    o1.z = acc[r][6] + bv1.z; o1.w = acc[r][7] + bv1.w;
    float* ob = &XP[((size_t)midx * MM + (m0 + ty * 8 + r)) * DD + nj0 + tx * 8];
    *(float4*)&ob[0] = o0;
    *(float4*)&ob[4] = o1;
  }
}

// ---------------------------------------------------------------------------
// Recurrent scan. 256 WGs x 512 threads, 8 groups (one per batch) x 32 WGs.
// CHANGES vs round 2 (diagnosis: VGPR_Count=128 -> 192 weight VGPRs spilled
// to scratch; per-thread __threadfence() x4/step caused L2 writeback storms
// interacting with acquire-poll invalidates -> 132 us/step):
//   * __launch_bounds__(512, 2): unlock 256 VGPR/thread so the 192 weight
//     VGPRs actually live in registers (1 WG/CU, 2 waves/SIMD).
//   * removed all per-thread __threadfence(); ordering carried by
//     __syncthreads() (per-thread vmcnt drain) + tid0 RELEASE fetch_add
//     (L2 writeback) / tid0 ACQUIRE poll (L1/L2 invalidate) + __syncthreads().
// ---------------------------------------------------------------------------
__device__ __forceinline__ float sigmoidf_(float x) {
  return 1.f / (1.f + __expf(-x));
}

__launch_bounds__(512, 2)
__global__ void scan_kernel(const float* __restrict__ XP,
                            const float* __restrict__ Wr,
                            const float* __restrict__ Wu,
                            const float* __restrict__ Wc,
                            float* __restrict__ hs,
                            float* __restrict__ r_buf,
                            unsigned* __restrict__ ctrs) {
  __shared__ float h_lds[DD];
  __shared__ float g_lds[DD];
  __shared__ float u_stage[32];

  int wg = blockIdx.x;
  int b = wg & 7;
  int w = wg >> 3;            // 0..31
  int tid = threadIdx.x;
  int wv = tid >> 6;          // wave 0..7
  int l = tid & 63;           // lane

  // ---- phase A layout: 16 groups (8 r + 8 u) x 4 cols, 32 k-lanes each ----
  int ga = wv * 2 + (l >> 5); // 0..15
  int sA = l & 31;
  bool isR = (ga < 8);
  int gA = isR ? ga : (ga - 8);      // 0..7
  int jA = w * 32 + gA * 4;          // global col base (4 cols)
  const float* WA = isR ? Wr : Wu;

  float4 wAv[32];                    // weights: k = sA + 32*kk   (128 VGPR)
#pragma unroll
  for (int kk = 0; kk < 32; ++kk)
    wAv[kk] = *(const float4*)&WA[(size_t)(DD + sA + 32 * kk) * DD + jA];

  // ---- phase B layout: wave wv owns 4 cols, full 64-lane K reduce ----
  int jB = w * 32 + wv * 4;
  float4 wBv[16];                    // weights: k = l + 64*i     (64 VGPR)
#pragma unroll
  for (int i = 0; i < 16; ++i)
    wBv[i] = *(const float4*)&Wc[(size_t)(DD + l + 64 * i) * DD + jB];

  unsigned* ctrA = &ctrs[b * 32];
  unsigned* ctrB = &ctrs[512 + b * 32];

  const float* xpR = XP + ((size_t)0 * BB + b) * SS * DD;
  const float* xpU = XP + ((size_t)1 * BB + b) * SS * DD;
  const float* xpC = XP + ((size_t)2 * BB + b) * SS * DD;
  float* hsb = hs + (size_t)b * SS * DD;
  float* rb = r_buf + (size_t)b * DD;

  long long wc0 = wall_clock64();
  const long long BUDGET = 2000000000LL;  // hang bailout only (~20 s)

  for (int t = 0; t < SS; ++t) {
    // prefetch xp (independent of h -- overlaps the spin)
    float4 xpA, xpC4;
    if (sA == 0) xpA = *(const float4*)&(isR ? xpR : xpU)[(size_t)t * DD + jA];
    if (l == 0) xpC4 = *(const float4*)&xpC[(size_t)t * DD + jB];

    // ---- wait for h_{t-1} (all 32 WGs of this group finished step t-1) ----
    if (t > 0) {
      if (tid == 0) {
        unsigned target = (unsigned)(32 * t);
        while (__hip_atomic_load(ctrB, __ATOMIC_ACQUIRE, __HIP_MEMORY_SCOPE_AGENT) < target) {
          if (wall_clock64() - wc0 > BUDGET) break;
          __builtin_amdgcn_s_sleep(2);
        }
      }
      __syncthreads();
    }

    // stage h into LDS (t=0: zeros)
    float4 hv4;
    if (tid < 256) {
      if (t == 0) { hv4.x = hv4.y = hv4.z = hv4.w = 0.f; }
      else hv4 = *(const float4*)&hsb[(size_t)(t - 1) * DD + tid * 4];
      *(float4*)&h_lds[tid * 4] = hv4;
    }
    __syncthreads();

    // ---- phase A: r,u = sigmoid(xp + h @ W_h) ----
    float a0 = 0.f, a1 = 0.f, a2 = 0.f, a3 = 0.f;
#pragma unroll
    for (int kk = 0; kk < 32; ++kk) {
      float hk = h_lds[sA + 32 * kk];
      float4 wv4 = wAv[kk];
      a0 += hk * wv4.x; a1 += hk * wv4.y; a2 += hk * wv4.z; a3 += hk * wv4.w;
    }
#pragma unroll
    for (int m = 16; m >= 1; m >>= 1) {
      a0 += __shfl_xor(a0, m); a1 += __shfl_xor(a1, m);
      a2 += __shfl_xor(a2, m); a3 += __shfl_xor(a3, m);
    }
    if (sA == 0) {
      float4 v;
      v.x = sigmoidf_(a0 + xpA.x); v.y = sigmoidf_(a1 + xpA.y);
      v.z = sigmoidf_(a2 + xpA.z); v.w = sigmoidf_(a3 + xpA.w);
      if (isR) *(float4*)&rb[jA] = v;
      else *(float4*)&u_stage[gA * 4] = v;
    }
    __syncthreads();   // drains each thread's stores (vmcnt) before barrier
    if (tid == 0)
      __hip_atomic_fetch_add(ctrA, 1u, __ATOMIC_RELEASE, __HIP_MEMORY_SCOPE_AGENT);

    // ---- wait for full r ----
    if (tid == 0) {
      unsigned target = (unsigned)(32 * (t + 1));
      while (__hip_atomic_load(ctrA, __ATOMIC_ACQUIRE, __HIP_MEMORY_SCOPE_AGENT) < target) {
        if (wall_clock64() - wc0 > BUDGET) break;
        __builtin_amdgcn_s_sleep(2);
      }
    }
    __syncthreads();

    // stage g = r * h
    if (tid < 256) {
      float4 r4 = *(const float4*)&rb[tid * 4];
      float4 g4;
      g4.x = r4.x * hv4.x; g4.y = r4.y * hv4.y;
      g4.z = r4.z * hv4.z; g4.w = r4.w * hv4.w;
      *(float4*)&g_lds[tid * 4] = g4;
    }
    __syncthreads();

    // ---- phase B: c = tanh(xp + (r*h) @ Wc_h); h' = (1-u)h + u c ----
    float c0 = 0.f, c1 = 0.f, c2 = 0.f, c3 = 0.f;
#pragma unroll
    for (int i = 0; i < 16; ++i) {
      float gk = g_lds[l + 64 * i];
      float4 wv4 = wBv[i];
      c0 += gk * wv4.x; c1 += gk * wv4.y; c2 += gk * wv4.z; c3 += gk * wv4.w;
    }
#pragma unroll
    for (int m = 32; m >= 1; m >>= 1) {
      c0 += __shfl_xor(c0, m); c1 += __shfl_xor(c1, m);
      c2 += __shfl_xor(c2, m); c3 += __shfl_xor(c3, m);
    }
    if (l == 0) {
      float4 cc;
      cc.x = tanhf(c0 + xpC4.x); cc.y = tanhf(c1 + xpC4.y);
      cc.z = tanhf(c2 + xpC4.z); cc.w = tanhf(c3 + xpC4.w);
      float4 uu = *(float4*)&u_stage[wv * 4];
      float4 hh = *(float4*)&h_lds[jB];
      float4 hn;
      hn.x = (1.f - uu.x) * hh.x + uu.x * cc.x;
      hn.y = (1.f - uu.y) * hh.y + uu.y * cc.y;
      hn.z = (1.f - uu.z) * hh.z + uu.z * cc.z;
      hn.w = (1.f - uu.w) * hh.w + uu.w * cc.w;
      *(float4*)&hsb[(size_t)t * DD + jB] = hn;
    }
    __syncthreads();   // drains h' stores before the release-add
    if (tid == 0)
      __hip_atomic_fetch_add(ctrB, 1u, __ATOMIC_RELEASE, __HIP_MEMORY_SCOPE_AGENT);
  }
}

// ---------------------------------------------------------------------------
// 6 LayerNorms over halves of hs. One wave per (b,s,half); 3 outputs each.
// ---------------------------------------------------------------------------
__launch_bounds__(256)
__global__ void ln_kernel(const float* __restrict__ hs,
                          const float* __restrict__ ln_scale,
                          const float* __restrict__ ln_bias,
                          float* __restrict__ out) {
  int wv = threadIdx.x >> 6, l = threadIdx.x & 63;
  int row = blockIdx.x * 4 + wv;   // 0..32767
  int half = row & 1;
  int bs = row >> 1;               // 0..16383

  const float* x = &hs[(size_t)bs * DD + half * DC];
  float4 v0 = *(const float4*)&x[l * 8];
  float4 v1 = *(const float4*)&x[l * 8 + 4];
  float sum = v0.x + v0.y + v0.z + v0.w + v1.x + v1.y + v1.z + v1.w;
  float sq = v0.x * v0.x + v0.y * v0.y + v0.z * v0.z + v0.w * v0.w +
             v1.x * v1.x + v1.y * v1.y + v1.z * v1.z + v1.w * v1.w;
#pragma unroll
  for (int m = 32; m >= 1; m >>= 1) {
    sum += __shfl_xor(sum, m);
    sq += __shfl_xor(sq, m);
  }
  float mu = sum * (1.f / 512.f);
  float var = sq * (1.f / 512.f) - mu * mu;
  float rs = rsqrtf(var + 1e-6f);

#pragma unroll
  for (int rep = 0; rep < 3; ++rep) {
    int i = half + rep * 2;
    float4 s0 = *(const float4*)&ln_scale[i * DC + l * 8];
    float4 s1 = *(const float4*)&ln_scale[i * DC + l * 8 + 4];
    float4 b0 = *(const float4*)&ln_bias[i * DC + l * 8];
    float4 b1 = *(const float4*)&ln_bias[i * DC + l * 8 + 4];
    float4 o0, o1;
    o0.x = (v0.x - mu) * rs * s0.x + b0.x;
    o0.y = (v0.y - mu) * rs * s0.y + b0.y;
    o0.z = (v0.z - mu) * rs * s0.z + b0.z;
    o0.w = (v0.w - mu) * rs * s0.w + b0.w;
    o1.x = (v1.x - mu) * rs * s1.x + b1.x;
    o1.y = (v1.y - mu) * rs * s1.y + b1.y;
    o1.z = (v1.z - mu) * rs * s1.z + b1.z;
    o1.w = (v1.w - mu) * rs * s1.w + b1.w;
    float* ob = &out[((size_t)i * MM + bs) * DC + l * 8];
    *(float4*)&ob[0] = o0;
    *(float4*)&ob[4] = o1;
  }
}

// ---------------------------------------------------------------------------
extern "C" void kernel_launch(void* const* d_in, const int* in_sizes, int n_in,
                              void* d_out, int out_size, void* d_ws, size_t ws_size,
                              hipStream_t stream) {
  const int* ids = (const int*)d_in[0];
  const float* emb_r = (const float*)d_in[1];
  const float* emb_i = (const float*)d_in[2];
  const float* Wr = (const float*)d_in[3];
  const float* br = (const float*)d_in[4];
  const float* Wu = (const float*)d_in[5];
  const float* bu = (const float*)d_in[6];
  const float* Wc = (const float*)d_in[7];
  const float* bc = (const float*)d_in[8];
  const float* ln_s = (const float*)d_in[9];
  const float* ln_b = (const float*)d_in[10];
  float* out = (float*)d_out;

  // ws layout (floats): XP[3][16384][1024] | hs[16384][1024] | r_buf[8][1024] | ctrs
  float* XP = (float*)d_ws;
  float* hs = XP + (size_t)3 * MM * DD;
  float* rb = hs + (size_t)MM * DD;
  unsigned* ctrs = (unsigned*)(rb + BB * DD);

  hipLaunchKernelGGL(init_kernel, dim3(1), dim3(1024), 0, stream, ctrs);
  hipLaunchKernelGGL(gemm_xproj, dim3((MM / GM_BM) * (NTOT / GM_BN)), dim3(256), 0, stream,
                     ids, emb_r, emb_i, Wr, Wu, Wc, br, bu, bc, XP);
  hipLaunchKernelGGL(scan_kernel, dim3(256), dim3(512), 0, stream,
                     XP, Wr, Wu, Wc, hs, rb, ctrs);
  hipLaunchKernelGGL(ln_kernel, dim3(32768 / 4), dim3(256), 0, stream,
                     hs, ln_s, ln_b, out);
}